// Round 18
// baseline (41.663 us; speedup 1.0000x reference)
//
#include <hip/hip_runtime.h>
#include <hip/hip_fp16.h>

#define SCALE (1.0f/16.0f)

typedef __attribute__((ext_vector_type(8))) _Float16 f16x8;
typedef __attribute__((ext_vector_type(4))) float f32x4;
typedef __attribute__((ext_vector_type(16))) float f32x16;
typedef __attribute__((ext_vector_type(4))) unsigned int u32x4;
typedef unsigned int u32;

__device__ __forceinline__ void gload16(const void* g, void* l) {
    __builtin_amdgcn_global_load_lds(
        (const __attribute__((address_space(1))) unsigned int*)g,
        (__attribute__((address_space(3))) unsigned int*)l, 16, 0, 0);
}
__device__ __forceinline__ __half2 asH2(u32 v) {
    union { u32 i; __half2 h; } u; u.i = v; return u.h;
}
__device__ __forceinline__ u32 asU32(__half2 h) {
    union { __half2 h; u32 i; } u; u.h = h; return u.i;
}
__device__ __forceinline__ int dupH2(float f) {
    __half h = __float2half_rn(f);
    __half2 d; d.x = h; d.y = h;
    union { __half2 h2; int i; } u; u.h2 = d; return u.i;
}

// ---------------- K1: prep = transpose (blocks 0..255) + permw (blocks 256..511) ----------------
__global__ void k_prep(const float* __restrict__ feat, __half* __restrict__ featT,
                       const float* __restrict__ wf, __half* __restrict__ wr) {
    __shared__ float t[64][65];
    int b = blockIdx.x;
    if (b < 256) {
        int cb = (b >> 6) << 6;
        int pb = (b & 63) << 6;
        int lx = threadIdx.x & 63, ly = threadIdx.x >> 6;
#pragma unroll
        for (int i = 0; i < 16; ++i) {
            int cl = i*4 + ly;
            t[cl][lx] = feat[(size_t)(cb + cl) * 4096 + pb + lx];
        }
        __syncthreads();
#pragma unroll
        for (int i = 0; i < 16; ++i) {
            int pl = i*4 + ly;
            featT[(size_t)(pb + pl) * 256 + cb + lx] = __float2half_rn(t[lx][pl]);
        }
    } else {
        int ch = (b - 256) * 256 + threadIdx.x;
        int l  = ch & 63;
        int sk = (ch >> 6) & 15;
        int ot = (ch >> 10) & 7;
        int j  = ch >> 13;
        int o = ot*32 + (l & 31);
        int k = j*256 + sk*16 + (l >> 5)*8;
        const float* src = wf + (size_t)o*2048 + k;
        f32x4 a = *(const f32x4*)src;
        f32x4 bb = *(const f32x4*)(src + 4);
        f16x8 p;
#pragma unroll
        for (int u = 0; u < 4; ++u) p[u] = (_Float16)a[u];
#pragma unroll
        for (int u = 0; u < 4; ++u) p[4+u] = (_Float16)bb[u];
        *((f16x8*)wr + ch) = p;
    }
}

// ---------------- K2: fused ROIAlign + GEMM, K split across blocks ----------------
// Grid 256: (n 0..127, kh 0..1). Block: 4 boxes (K-half), full 49-hw tile, all 256 o.
// 512 thr = 8 waves; waves 0-3 produce (stage/pool), 4-7 consume (W prefetch + GEMM).
// 4 main phases; f32 partials to ws; reduce kernel applies bias+relu.
__global__ void __launch_bounds__(512) k_fused(
    const __half* __restrict__ featT,
    const float* __restrict__ boxes,
    const __half* __restrict__ wr,
    float* __restrict__ part)
{
    __shared__ char patch[2][28672];     // ring-2: [buf][y 7][px 8][c 256] fp16
    __shared__ char Pl[2][32768];        // [buf][64 hw][256 c] fp16, XOR swizzle (e&31)
    __shared__ int4 tabs[4][2][7];       // [jj][x/y][idx]
    __shared__ int  pbs[4][2];
    __shared__ float bx_lds[16];         // this block's 4 boxes

    int tid = threadIdx.x;
    int lane = tid & 63, wid = tid >> 6;
    int r31 = lane & 31, l5 = lane >> 5;
    int bid = blockIdx.x;
    int n  = bid & 127;
    int kh = bid >> 7;
    bool producer = wid < 4;

    int nb_base = (n & 15) * 8;
    int off = n >> 4;
    int t3 = off + (off >= 4 ? 1 : 0);
    int ci = t3 / 3, cj = t3 - ci*3;

    if (tid < 16) bx_lds[tid] = boxes[(nb_base + kh*4)*4 + tid];
    // zero Pl pad rows 49..63 (both buffers)
    for (int i = tid; i < 15*32*2; i += 512) {
        int b = i / (15*32);
        int rem = i - b*(15*32);
        int row = 49 + (rem >> 5), slot = rem & 31;
        *(u32x4*)(Pl[b] + row*512 + slot*16) = (u32x4){0,0,0,0};
    }

    auto tablesW = [&](int jj) {         // waves 0,1 (isy = wid)
        if (wid < 2) {
            int isy = wid;
            float bx1 = bx_lds[jj*4+0], by1 = bx_lds[jj*4+1];
            float bx2 = bx_lds[jj*4+2], by2 = bx_lds[jj*4+3];
            float w3 = (bx2-bx1)*(1.f/3.f), h3 = (by2-by1)*(1.f/3.f);
            float org  = isy ? (by1 + ci*h3)*SCALE - 0.5f : (bx1 + cj*w3)*SCALE - 0.5f;
            float step = (isy ? h3 : w3) * (SCALE*(1.f/14.f));
            float sc = isy ? 0.25f : 1.f;
            float p = org + ((float)lane + 0.5f)*step;
            float pc = fminf(fmaxf(p, 0.f), 63.f);
            float fl = fminf(floorf(pc), 62.f);
            float fr = pc - fl;
            float c0 = __shfl(fl, 2*lane);
            float c1 = __shfl(fl, 2*lane+1);
            float f  = __shfl(fr, 2*lane);
            float f2 = __shfl(fr, 2*lane+1);
            float fl0 = __shfl(fl, 0);
            int base = min((int)fl0, 56);
            float d = c1 - c0;
            float a0 = sc*((1.f-f) + (1.f-d)*(1.f-f2));
            float a1 = sc*(f + (1.f-d)*f2 + d*(1.f-f2));
            float a2 = sc*(d*f2);
            if (lane < 7) {
                int4 e;
                e.x = (int)c0 - base;
                e.y = dupH2(a0); e.z = dupH2(a1); e.w = dupH2(a2);
                tabs[jj][isy][lane] = e;
            }
            if (lane == 0) pbs[jj][isy] = base;
        }
    };

    auto stage = [&](int jj) {           // 7 gload16 per producer wave -> patch[jj&1]
        int xb = pbs[jj][0], yb = pbs[jj][1];
        char* pd = patch[jj & 1];
#pragma unroll
        for (int i = 0; i < 7; ++i) {
            int seg = wid + 4*i;
            int row = seg >> 2, q = seg & 3;
            const __half* src = featT + ((size_t)((yb + row)*64 + xb))*256 + q*512 + lane*8;
            gload16(src, pd + row*4096 + q*1024);
        }
    };

    auto pool = [&](int jj) {            // 49 positions, LDS-only, fully unrolled
        int buf = jj & 1;
        int co = tid & 31;
        int e0 = tid >> 5;
        const char* pb = patch[jj & 1] + co*16;
#pragma unroll
        for (int it = 0; it < 7; ++it) {
            int e = e0 + it*8;
            bool on = e < 49;
            int ec = on ? e : 0;
            int h = (ec*37) >> 8, w = ec - h*7;
            int4 tx = tabs[jj][0][w], ty = tabs[jj][1][h];
            int px0 = tx.x, py0 = ty.x;
            int lx2 = min(px0 + 2, 7), ly2 = min(py0 + 2, 6);
            const char* r0 = pb + (py0*8 + px0)*512;
            const char* r1 = pb + (min(py0+1,6)*8 + px0)*512;
            const char* r2 = pb + (ly2*8 + px0)*512;
            int dx2 = (lx2 - px0)*512;
            u32x4 F00 = *(const u32x4*)(r0);
            u32x4 F01 = *(const u32x4*)(r0 + 512);
            u32x4 F02 = *(const u32x4*)(r0 + dx2);
            u32x4 F10 = *(const u32x4*)(r1);
            u32x4 F11 = *(const u32x4*)(r1 + 512);
            u32x4 F12 = *(const u32x4*)(r1 + dx2);
            u32x4 F20 = *(const u32x4*)(r2);
            u32x4 F21 = *(const u32x4*)(r2 + 512);
            u32x4 F22 = *(const u32x4*)(r2 + dx2);
            __half2 xa = asH2(tx.y), xb2 = asH2(tx.z), xc = asH2(tx.w);
            __half2 ya = asH2(ty.y), yb2 = asH2(ty.z), yc = asH2(ty.w);
            u32x4 res;
#pragma unroll
            for (int s = 0; s < 4; ++s) {
                __half2 q0 = __hfma2(asH2(F02[s]), xc, __hfma2(asH2(F01[s]), xb2, __hmul2(asH2(F00[s]), xa)));
                __half2 q1 = __hfma2(asH2(F12[s]), xc, __hfma2(asH2(F11[s]), xb2, __hmul2(asH2(F10[s]), xa)));
                __half2 q2 = __hfma2(asH2(F22[s]), xc, __hfma2(asH2(F21[s]), xb2, __hmul2(asH2(F20[s]), xa)));
                res[s] = asU32(__hfma2(q2, yc, __hfma2(q1, yb2, __hmul2(q0, ya))));
            }
            if (on)
                *(u32x4*)(Pl[buf] + ec*512 + ((co*16) ^ ((ec & 31) << 4))) = res;
        }
    };

    // ---- consumer: 2 o-tiles x 16 sk x 2 hw-tiles; W half-interleaved reload ----
    int cw = wid - 4;
    u32x4 Wf[32];
    f32x16 accA0, accA1, accB0, accB1;
#pragma unroll
    for (int i = 0; i < 16; ++i) { accA0[i]=0.f; accA1[i]=0.f; accB0[i]=0.f; accB1[i]=0.f; }

    auto prefW_half = [&](int j, int sb) {
        int jg = kh*4 + j;
#pragma unroll
        for (int t = 0; t < 2; ++t) {
            int otg = cw*2 + t;
            const u32x4* wb = (const u32x4*)wr + ((size_t)((jg*8 + otg)*16))*64 + lane;
#pragma unroll
            for (int s = 0; s < 8; ++s) Wf[t*16 + sb*8 + s] = wb[(sb*8 + s)*64];
        }
    };

    auto gemm_half = [&](int j, int sb) {
        const char* plb = (j & 1) ? Pl[1] : Pl[0];
#pragma unroll
        for (int s = 0; s < 8; ++s) {
            int sk = sb*8 + s;
            int by0 = r31*512 + ((sk*32 + l5*16) ^ (r31 << 4));
            int by1 = (32 + r31)*512 + ((sk*32 + l5*16) ^ (r31 << 4));
            f16x8 pf0 = *(const f16x8*)(plb + by0);
            f16x8 pf1 = *(const f16x8*)(plb + by1);
            accA0 = __builtin_amdgcn_mfma_f32_32x32x16_f16(
                __builtin_bit_cast(f16x8, Wf[sk]), pf0, accA0, 0, 0, 0);
            accA1 = __builtin_amdgcn_mfma_f32_32x32x16_f16(
                __builtin_bit_cast(f16x8, Wf[sk]), pf1, accA1, 0, 0, 0);
            accB0 = __builtin_amdgcn_mfma_f32_32x32x16_f16(
                __builtin_bit_cast(f16x8, Wf[16 + sk]), pf0, accB0, 0, 0, 0);
            accB1 = __builtin_amdgcn_mfma_f32_32x32x16_f16(
                __builtin_bit_cast(f16x8, Wf[16 + sk]), pf1, accB1, 0, 0, 0);
        }
    };

    // ---- prologue ----
    __syncthreads();                       // bx_lds + Pl pads visible
    tablesW(0); tablesW(1); tablesW(2); tablesW(3);
    __syncthreads();                       // tabs/pbs visible
    if (producer) {
        stage(0); stage(1);                // 14 DMAs in flight
        asm volatile("s_waitcnt vmcnt(7)" ::: "memory");   // box0 landed
        __builtin_amdgcn_sched_barrier(0);
        pool(0);
        asm volatile("s_waitcnt lgkmcnt(0)" ::: "memory");
    } else {
        prefW_half(0, 0); prefW_half(0, 1);   // fly across the barrier
    }
    __builtin_amdgcn_s_barrier();
    __builtin_amdgcn_sched_barrier(0);

    // ---- main loop: 4 phases ----
#pragma unroll
    for (int j = 0; j < 4; ++j) {
        if (producer) {
            if (j == 0) stage(2);
            else if (j == 1) stage(3);
            if (j < 3) {
                if (j < 2) asm volatile("s_waitcnt vmcnt(7)" ::: "memory");
                else       asm volatile("s_waitcnt vmcnt(0)" ::: "memory");
                __builtin_amdgcn_sched_barrier(0);
                pool(j+1);
            }
            asm volatile("s_waitcnt lgkmcnt(0)" ::: "memory");
        } else {
            gemm_half(j, 0);
            if (j < 3) prefW_half(j+1, 0);
            gemm_half(j, 1);
            if (j < 3) prefW_half(j+1, 1);
            asm volatile("s_waitcnt lgkmcnt(0)" ::: "memory");
        }
        __builtin_amdgcn_s_barrier();
        __builtin_amdgcn_sched_barrier(0);
    }

    // ---- epilogue: consumers write f32 partials part[kh][n][o][hw] ----
    if (!producer) {
        float* pb = part + ((size_t)(kh*128 + n)) * 12544;
#pragma unroll
        for (int t = 0; t < 2; ++t) {
#pragma unroll
            for (int hwt = 0; hwt < 2; ++hwt) {
                f32x16 a = t ? (hwt ? accB1 : accB0) : (hwt ? accA1 : accA0);
                int hw = hwt*32 + r31;
                bool ok = hw < 49;
                int otb = (cw*2 + t)*32;
#pragma unroll
                for (int reg = 0; reg < 16; ++reg) {
                    int o = otb + (reg & 3) + 8*(reg >> 2) + 4*l5;
                    if (ok) pb[(size_t)o*49 + hw] = a[reg];
                }
            }
        }
    }
}

// ---------------- K3: reduce 2 partials + bias + relu ----------------
__global__ void k_reduce(const float* __restrict__ part, const float* __restrict__ bfuse,
                         float* __restrict__ out) {
    int i4 = blockIdx.x * 256 + threadIdx.x;      // 0..401407
    f32x4 a = ((const f32x4*)part)[i4];
    f32x4 b = ((const f32x4*)(part + 1605632))[i4];
    int base = i4 * 4;
    f32x4 r;
#pragma unroll
    for (int u = 0; u < 4; ++u) {
        int o = ((base + u) / 49) & 255;
        r[u] = fmaxf(a[u] + b[u] + bfuse[o], 0.f);
    }
    ((f32x4*)out)[i4] = r;
}

extern "C" void kernel_launch(void* const* d_in, const int* in_sizes, int n_in,
                              void* d_out, int out_size, void* d_ws, size_t ws_size,
                              hipStream_t stream) {
    const float* feat  = (const float*)d_in[0];   // [256,64,64]
    const float* boxes = (const float*)d_in[1];   // [128,4]
    const float* wf    = (const float*)d_in[2];   // [256,2048]
    const float* bfuse = (const float*)d_in[3];   // [256]
    float* out = (float*)d_out;                   // [128,256,7,7]

    char* ws = (char*)d_ws;
    __half* wr    = (__half*)ws;                  // 1 MB (permuted W, fp16)
    __half* featT = (__half*)(ws + (1u<<20));     // 2 MB (fp16 feat, pix-major)
    float*  part  = (float*)(ws + (4u<<20));      // 12.8 MB (2 K-half partials)

    k_prep<<<512, 256, 0, stream>>>(feat, featT, wf, wr);
    k_fused<<<256, 512, 0, stream>>>(featT, boxes, wr, part);
    k_reduce<<<1568, 256, 0, stream>>>(part, bfuse, out);
}

// Round 19
// 29.550 us; speedup vs baseline: 1.4099x; 1.4099x over previous
//
#include <hip/hip_runtime.h>
#include <hip/hip_fp16.h>

#define SCALE (1.0f/16.0f)

typedef __attribute__((ext_vector_type(8))) _Float16 f16x8;
typedef __attribute__((ext_vector_type(4))) float f32x4;
typedef __attribute__((ext_vector_type(16))) float f32x16;
typedef __attribute__((ext_vector_type(4))) unsigned int u32x4;
typedef unsigned int u32;

__device__ __forceinline__ void gload16(const void* g, void* l) {
    __builtin_amdgcn_global_load_lds(
        (const __attribute__((address_space(1))) unsigned int*)g,
        (__attribute__((address_space(3))) unsigned int*)l, 16, 0, 0);
}
__device__ __forceinline__ __half2 asH2(u32 v) {
    union { u32 i; __half2 h; } u; u.i = v; return u.h;
}
__device__ __forceinline__ u32 asU32(__half2 h) {
    union { __half2 h; u32 i; } u; u.h = h; return u.i;
}
__device__ __forceinline__ int dupH2(float f) {
    __half h = __float2half_rn(f);
    __half2 d; d.x = h; d.y = h;
    union { __half2 h2; int i; } u; u.h2 = d; return u.i;
}

// ---------------- K1: prep = transpose (blocks 0..255) + permw (blocks 256..511) ----------------
__global__ void k_prep(const float* __restrict__ feat, __half* __restrict__ featT,
                       const float* __restrict__ wf, __half* __restrict__ wr) {
    __shared__ float t[64][65];
    int b = blockIdx.x;
    if (b < 256) {
        int cb = (b >> 6) << 6;
        int pb = (b & 63) << 6;
        int lx = threadIdx.x & 63, ly = threadIdx.x >> 6;
#pragma unroll
        for (int i = 0; i < 16; ++i) {
            int cl = i*4 + ly;
            t[cl][lx] = feat[(size_t)(cb + cl) * 4096 + pb + lx];
        }
        __syncthreads();
#pragma unroll
        for (int i = 0; i < 16; ++i) {
            int pl = i*4 + ly;
            featT[(size_t)(pb + pl) * 256 + cb + lx] = __float2half_rn(t[lx][pl]);
        }
    } else {
        int ch = (b - 256) * 256 + threadIdx.x;
        int l  = ch & 63;
        int sk = (ch >> 6) & 15;
        int ot = (ch >> 10) & 7;
        int j  = ch >> 13;
        int o = ot*32 + (l & 31);
        int k = j*256 + sk*16 + (l >> 5)*8;
        const float* src = wf + (size_t)o*2048 + k;
        f32x4 a = *(const f32x4*)src;
        f32x4 bb = *(const f32x4*)(src + 4);
        f16x8 p;
#pragma unroll
        for (int u = 0; u < 4; ++u) p[u] = (_Float16)a[u];
#pragma unroll
        for (int u = 0; u < 4; ++u) p[4+u] = (_Float16)bb[u];
        *((f16x8*)wr + ch) = p;
    }
}

// ---------------- K2: fused ROIAlign + GEMM, prod/cons + raw barriers + counted vmcnt ----------------
// Grid 256: (n 0..127, hh 0..1), hw split 25/24. 512 thr = 8 waves; waves 0-3 produce,
// waves 4-7 consume. Pool fully unrolled (predicated) so all LDS latency chains overlap.
__global__ void __launch_bounds__(512) k_fused(
    const __half* __restrict__ featT,
    const float* __restrict__ boxes,
    const __half* __restrict__ wr,
    const float* __restrict__ bfuse,
    float* __restrict__ out)
{
    __shared__ char patch[3][28672];
    __shared__ char Pl[2][16384];
    __shared__ int4 tabs[4][2][7];
    __shared__ int  pbs[4][2];
    __shared__ float bx_lds[32];

    int tid = threadIdx.x;
    int lane = tid & 63, wid = tid >> 6;
    int r31 = lane & 31, l5 = lane >> 5;
    int bid = blockIdx.x;
    int n  = bid & 127;
    int hh = bid >> 7;
    int hw0 = hh * 25;
    int HWn = hh ? 24 : 25;
    bool producer = wid < 4;

    int nb_base = (n & 15) * 8;
    int off = n >> 4;
    int t3 = off + (off >= 4 ? 1 : 0);
    int ci = t3 / 3, cj = t3 - ci*3;

    if (tid < 32) bx_lds[tid] = boxes[nb_base*4 + tid];
    {
        int padrows = 32 - HWn;                       // 7 or 8
        for (int i = tid; i < padrows*32*2; i += 512) {
            int b = i / (padrows*32);
            int rem = i - b*(padrows*32);
            int row = HWn + (rem >> 5), slot = rem & 31;
            *(u32x4*)(Pl[b] + row*512 + slot*16) = (u32x4){0,0,0,0};
        }
    }

    auto tablesW = [&](int jj) {
        if (wid < 2) {
            int isy = wid;
            float bx1 = bx_lds[jj*4+0], by1 = bx_lds[jj*4+1];
            float bx2 = bx_lds[jj*4+2], by2 = bx_lds[jj*4+3];
            float w3 = (bx2-bx1)*(1.f/3.f), h3 = (by2-by1)*(1.f/3.f);
            float org  = isy ? (by1 + ci*h3)*SCALE - 0.5f : (bx1 + cj*w3)*SCALE - 0.5f;
            float step = (isy ? h3 : w3) * (SCALE*(1.f/14.f));
            float sc = isy ? 0.25f : 1.f;
            float p = org + ((float)lane + 0.5f)*step;
            float pc = fminf(fmaxf(p, 0.f), 63.f);
            float fl = fminf(floorf(pc), 62.f);
            float fr = pc - fl;
            float c0 = __shfl(fl, 2*lane);
            float c1 = __shfl(fl, 2*lane+1);
            float f  = __shfl(fr, 2*lane);
            float f2 = __shfl(fr, 2*lane+1);
            float fl0 = __shfl(fl, 0);
            int base = min((int)fl0, 56);
            float d = c1 - c0;
            float a0 = sc*((1.f-f) + (1.f-d)*(1.f-f2));
            float a1 = sc*(f + (1.f-d)*f2 + d*(1.f-f2));
            float a2 = sc*(d*f2);
            if (lane < 7) {
                int4 e;
                e.x = (int)c0 - base;
                e.y = dupH2(a0); e.z = dupH2(a1); e.w = dupH2(a2);
                tabs[jj & 3][isy][lane] = e;
            }
            if (lane == 0) pbs[jj & 3][isy] = base;
        }
    };

    auto stage = [&](int jj) {           // exactly 7 gload16 per producer wave
        int xb = pbs[jj & 3][0], yb = pbs[jj & 3][1];
        char* pd = patch[jj % 3];
#pragma unroll
        for (int i = 0; i < 7; ++i) {
            int seg = wid + 4*i;
            int row = seg >> 2, q = seg & 3;
            const __half* src = featT + ((size_t)((yb + row)*64 + xb))*256 + q*512 + lane*8;
            gload16(src, pd + row*4096 + q*1024);
        }
    };

    // pool: compile-time 4-iteration predicated unroll — all LDS chains overlap
    auto pool = [&](int jj) {
        int buf = jj & 1;
        int co = tid & 31;
        int e0 = tid >> 5;
        const char* pb = patch[jj % 3] + co*16;
#pragma unroll
        for (int it = 0; it < 4; ++it) {
            if (it*8 < HWn) {                        // wave-uniform guard
                int e = e0 + it*8;
                bool on = e < HWn;
                int ec = on ? e : 0;
                int g = hw0 + ec;
                int h = (g*37) >> 8, w = g - h*7;
                int4 tx = tabs[jj & 3][0][w], ty = tabs[jj & 3][1][h];
                int px0 = tx.x, py0 = ty.x;
                int lx2 = min(px0 + 2, 7), ly2 = min(py0 + 2, 6);
                const char* r0 = pb + (py0*8 + px0)*512;
                const char* r1 = pb + (min(py0+1,6)*8 + px0)*512;
                const char* r2 = pb + (ly2*8 + px0)*512;
                int dx2 = (lx2 - px0)*512;
                u32x4 F00 = *(const u32x4*)(r0);
                u32x4 F01 = *(const u32x4*)(r0 + 512);
                u32x4 F02 = *(const u32x4*)(r0 + dx2);
                u32x4 F10 = *(const u32x4*)(r1);
                u32x4 F11 = *(const u32x4*)(r1 + 512);
                u32x4 F12 = *(const u32x4*)(r1 + dx2);
                u32x4 F20 = *(const u32x4*)(r2);
                u32x4 F21 = *(const u32x4*)(r2 + 512);
                u32x4 F22 = *(const u32x4*)(r2 + dx2);
                __half2 xa = asH2(tx.y), xb2 = asH2(tx.z), xc = asH2(tx.w);
                __half2 ya = asH2(ty.y), yb2 = asH2(ty.z), yc = asH2(ty.w);
                u32x4 res;
#pragma unroll
                for (int s = 0; s < 4; ++s) {
                    __half2 q0 = __hfma2(asH2(F02[s]), xc, __hfma2(asH2(F01[s]), xb2, __hmul2(asH2(F00[s]), xa)));
                    __half2 q1 = __hfma2(asH2(F12[s]), xc, __hfma2(asH2(F11[s]), xb2, __hmul2(asH2(F10[s]), xa)));
                    __half2 q2 = __hfma2(asH2(F22[s]), xc, __hfma2(asH2(F21[s]), xb2, __hmul2(asH2(F20[s]), xa)));
                    res[s] = asU32(__hfma2(q2, yc, __hfma2(q1, yb2, __hmul2(q0, ya))));
                }
                if (on)
                    *(u32x4*)(Pl[buf] + ec*512 + ((co*16) ^ ((ec & 31) << 4))) = res;
            }
        }
    };

    // consumer: 2 o-tiles x 16 sk, half-interleaved reload
    int cw = wid - 4;
    u32x4 Wf[32];
    f32x16 acc0, acc1;
#pragma unroll
    for (int i = 0; i < 16; ++i) { acc0[i] = 0.f; acc1[i] = 0.f; }

    auto prefW_half = [&](int j, int sb) {
#pragma unroll
        for (int t = 0; t < 2; ++t) {
            int otg = cw*2 + t;
            const u32x4* wb = (const u32x4*)wr + ((size_t)((j*8 + otg)*16))*64 + lane;
#pragma unroll
            for (int s = 0; s < 8; ++s) Wf[t*16 + sb*8 + s] = wb[(sb*8 + s)*64];
        }
    };

    auto gemm_half = [&](int j, int sb) {
        const char* plb = (j & 1) ? Pl[1] : Pl[0];
#pragma unroll
        for (int s = 0; s < 8; ++s) {
            int sk = sb*8 + s;
            int byo = r31*512 + ((sk*32 + l5*16) ^ (r31 << 4));
            f16x8 pf = *(const f16x8*)(plb + byo);
            acc0 = __builtin_amdgcn_mfma_f32_32x32x16_f16(
                __builtin_bit_cast(f16x8, Wf[sk]), pf, acc0, 0, 0, 0);
            acc1 = __builtin_amdgcn_mfma_f32_32x32x16_f16(
                __builtin_bit_cast(f16x8, Wf[16 + sk]), pf, acc1, 0, 0, 0);
        }
    };

    // ---- prologue ----
    __syncthreads();                       // bx_lds + pads visible
    tablesW(0); tablesW(1); tablesW(2); tablesW(3);
    __syncthreads();                       // tabs/pbs visible
    if (producer) {
        stage(0); stage(1); stage(2);
        asm volatile("s_waitcnt vmcnt(14)" ::: "memory");
        __builtin_amdgcn_sched_barrier(0);
        pool(0);
        asm volatile("s_waitcnt lgkmcnt(0)" ::: "memory");
    } else {
        prefW_half(0, 0); prefW_half(0, 1);
    }
    __builtin_amdgcn_s_barrier();
    __builtin_amdgcn_sched_barrier(0);

    // ---- main loop ----
#pragma unroll
    for (int j = 0; j < 8; ++j) {
        if (producer) {
            if (j < 5) stage(j+3);
            if (j < 7) {
                if (j < 5)       asm volatile("s_waitcnt vmcnt(14)" ::: "memory");
                else if (j == 5) asm volatile("s_waitcnt vmcnt(7)"  ::: "memory");
                else             asm volatile("s_waitcnt vmcnt(0)"  ::: "memory");
                __builtin_amdgcn_sched_barrier(0);
                pool(j+1);
            }
            if (j < 4) tablesW(j+4);
            asm volatile("s_waitcnt lgkmcnt(0)" ::: "memory");
        } else {
            gemm_half(j, 0);
            if (j < 7) prefW_half(j+1, 0);
            gemm_half(j, 1);
            if (j < 7) prefW_half(j+1, 1);
            asm volatile("s_waitcnt lgkmcnt(0)" ::: "memory");
        }
        __builtin_amdgcn_s_barrier();
        __builtin_amdgcn_sched_barrier(0);
    }

    // ---- epilogue: consumers write out (bias + relu) ----
    if (!producer) {
        int hw = hw0 + r31;
        bool ok = r31 < HWn;
        float* ob = out + (size_t)n*12544 + hw;
#pragma unroll
        for (int t = 0; t < 2; ++t) {
            f32x16 a = t ? acc1 : acc0;
            int otb = (cw*2 + t)*32;
#pragma unroll
            for (int reg = 0; reg < 16; ++reg) {
                int o = otb + (reg & 3) + 8*(reg >> 2) + 4*l5;
                float v = a[reg] + bfuse[o];
                if (ok) ob[(size_t)o*49] = fmaxf(v, 0.f);
            }
        }
    }
}

extern "C" void kernel_launch(void* const* d_in, const int* in_sizes, int n_in,
                              void* d_out, int out_size, void* d_ws, size_t ws_size,
                              hipStream_t stream) {
    const float* feat  = (const float*)d_in[0];
    const float* boxes = (const float*)d_in[1];
    const float* wf    = (const float*)d_in[2];
    const float* bfuse = (const float*)d_in[3];
    float* out = (float*)d_out;

    char* ws = (char*)d_ws;
    __half* wr    = (__half*)ws;                  // 1 MB (permuted W, fp16)
    __half* featT = (__half*)(ws + (1u<<20));     // 2 MB (fp16 feat, pix-major)

    k_prep<<<512, 256, 0, stream>>>(feat, featT, wf, wr);
    k_fused<<<256, 512, 0, stream>>>(featT, boxes, wr, bfuse, out);
}